// Round 3
// baseline (213.948 us; speedup 1.0000x reference)
//
#include <hip/hip_runtime.h>
#include <math.h>

// DTW 2048x2048, squared-diff cost, out = sqrt(DTW[2047][2047]).
//
// Skew-1 wave pipeline, NW=8 waves (512 thr) on one CU, R=4 rows/lane.
// Lane l of wave w owns rows 4*(64w+l)..+3; at wave-step t it computes
// column j = t - l for its 4 rows (serial min3+fma chain).
//
// WHY 8 waves (round-3 change): with NW=4 each SIMD held ONE wave, so the
// carried chain (dpp + 8x(min3+fma) = 17 dep ops at ~8.5cy each = 144cy)
// was fully exposed -- in-order issue has nothing to fill stalls with, and
// rounds 1/2 showed the compiler won't interleave software chains for a
// single wave. NW=8 -> 2 waves/SIMD: (a) chain halves to dpp+4x(min3+fma)
// = 9 dep ops ~ 76cy; (b) the second wave's instructions fill the first
// wave's stall slots (hardware round-robin issue). Cost: GTOT 2496->3008.
//
// Zero per-step LDS reads: per 64-step block each wave does TWO coalesced
// ds_read_b32 (y[tau0+lane], ring[tau0+lane]); per step, v_readlane(blk, s)
// (compile-time s) yields the wave-uniform y[tau0+s] / ring[tau0+s], which
// are injected into two DPP wave_shr:1 conveyors:
//   yconv: lane l holds y[t-l] (its column's y)
//   u    : lane l holds lane l-1's row-3 value (above/diag input); lane 0
//          gets the ring injection (row above the strip).
//
// min3 via unsigned-int bitcast min (all DP values non-negative; IEEE
// ordering == unsigned ordering): fuses to v_min3_u32. (Round 2 showed
// fminf(fminf()) also fused -- kept for guarantee, it's perf-neutral.)
//
// Guard-free: INFV=1e30 absorbs adds (1e30 + d^2 == 1e30 in fp32), so
// inactive-lane "commits" are idempotent; OOB ring writes (j<0 on ramp-in,
// j>=2048 on ramp-out) land in pad regions. Every block tau0 in [0,2048]
// runs the identical unrolled body. Output is stored at the unique step
// (tau0==2048, s==62, w=NW-1, lane 63) where j==2047.
//
// Ring: unwrapped rows, PAD=64 left pad, cols -64..2111 valid. All lanes
// write their row-3 value each step; lane 63 (true strip boundary) writes
// each column last within the wave, and DSKEW=128 + barrier every 64 steps
// guarantees the producer completed wave-step tau0+127 >= j+63 for every
// column j <= tau0+63 the consumer's block-top read touches.

#define NLEN  2048
#define NW    8
#define CSTEP 64
#define DSKEW 128
#define PAD   64
#define RROW  (PAD + 2112)                        // cols -64..2111
#define GTOT  (NLEN + CSTEP + (NW - 1) * DSKEW)   // 3008: last block w=7, tau0=2048
#define INFV  1e30f

__device__ __forceinline__ float dpp_shr1(float v, float inj) {
    int r = __builtin_amdgcn_update_dpp(
        __builtin_bit_cast(int, inj), __builtin_bit_cast(int, v),
        0x138 /*wave_shr:1*/, 0xF, 0xF, false /*lane0 keeps old=inj*/);
    return __builtin_bit_cast(float, r);
}
__device__ __forceinline__ float rdlane(float v, int l) {
    return __builtin_bit_cast(float,
        __builtin_amdgcn_readlane(__builtin_bit_cast(int, v), l));
}
// 3-input min on non-negative floats via unsigned bit-pattern compare;
// umin+umin fuses to a single v_min3_u32.
__device__ __forceinline__ float min3f(float a, float b, float c) {
    unsigned ia = __builtin_bit_cast(unsigned, a);
    unsigned ib = __builtin_bit_cast(unsigned, b);
    unsigned ic = __builtin_bit_cast(unsigned, c);
    unsigned m  = __builtin_elementwise_min(
                      __builtin_elementwise_min(ia, ib), ic);
    return __builtin_bit_cast(float, m);
}

__global__ __launch_bounds__(512, 1) void dtw_kernel(const float* __restrict__ X,
                                                     const float* __restrict__ Y,
                                                     float* __restrict__ out) {
    __shared__ __align__(16) float yS[NLEN];
    __shared__ float ring[(NW + 1) * RROW];

    const int tid  = threadIdx.x;
    const int w    = tid >> 6;
    const int lane = tid & 63;

    {
        const float4* Y4 = (const float4*)Y;
        float4* y4 = (float4*)yS;
        y4[tid] = Y4[tid];                         // 512 x float4 = 2048
    }
    // Entire ring INFV: virtual row -1, pads, and unwritten tails.
    for (int k = tid; k < (NW + 1) * RROW; k += 512) ring[k] = INFV;
    __syncthreads();

    float x0, x1, x2, x3;
    {
        const float4 xa = *(const float4*)&X[tid * 4];
        x0 = xa.x; x1 = xa.y; x2 = xa.z; x3 = xa.w;
    }

    float v0 = INFV, v1 = INFV, v2 = INFV, v3 = INFV;
    float uprev = (tid == 0) ? 0.0f : INFV;   // DTW[-1][-1]=0 seed
    float yconv = 0.0f;                       // y DPP conveyor

    const float* ringR = ring + w * RROW + PAD;
    float*       ringW = ring + (w + 1) * RROW + PAD;

    for (int gb = 0; gb < GTOT; gb += CSTEP) {
        const int tau0 = gb - w * DSKEW;

        if (tau0 >= 0 && tau0 <= NLEN) {
            int yi = tau0 + lane;                    // clamp for tau0==2048
            if (yi >= NLEN) yi = NLEN - 1;
            const float yblk = yS[yi];               // 1 coalesced ds_read
            const float rblk = ringR[tau0 + lane];   // 1 coalesced ds_read
            float* wp = ringW + (tau0 - lane);
            const bool isout = (tau0 == NLEN) & (w == NW - 1) & (lane == 63);

            #pragma unroll
            for (int s = 0; s < CSTEP; ++s) {
                const float yu = rdlane(yblk, s);    // y[tau0+s] (scalar)
                const float ru = rdlane(rblk, s);    // ring[tau0+s] (scalar)
                yconv = dpp_shr1(yconv, yu);         // lane l: y[tau0+s-l]
                const float u = dpp_shr1(v3, ru);    // above value
                float d0 = x0 - yconv; float nv0 = fmaf(d0, d0, min3f(v0, uprev, u));
                float d1 = x1 - yconv; float nv1 = fmaf(d1, d1, min3f(v1, v0, nv0));
                float d2 = x2 - yconv; float nv2 = fmaf(d2, d2, min3f(v2, v1, nv1));
                float d3 = x3 - yconv; float nv3 = fmaf(d3, d3, min3f(v3, v2, nv2));
                wp[s] = nv3;
                uprev = u;
                v0 = nv0; v1 = nv1; v2 = nv2; v3 = nv3;
                if (s == 62 && isout) out[0] = sqrtf(nv3);  // j == 2047
            }
        }
        __syncthreads();
    }
}

extern "C" void kernel_launch(void* const* d_in, const int* in_sizes, int n_in,
                              void* d_out, int out_size, void* d_ws, size_t ws_size,
                              hipStream_t stream) {
    const float* x = (const float*)d_in[0];
    const float* y = (const float*)d_in[1];
    (void)in_sizes; (void)n_in; (void)out_size; (void)d_ws; (void)ws_size;
    dtw_kernel<<<1, 512, 0, stream>>>(x, y, (float*)d_out);
}